// Round 1
// baseline (485.097 us; speedup 1.0000x reference)
//
#include <hip/hip_runtime.h>

#define BATCH 32
#define IC 16
#define OC 32
#define SI 32
#define KS 3
#define SO 30

#define ROWS 4                 // output rows per block band
#define XROWS (ROWS + KS - 1)  // 6 input rows staged
#define XCOLS 34               // 32 input cols + 2 window slack (zero-padded)
#define NBANDS 8               // ceil(30/4)
#define RTOT (IC * KS * KS)    // 144 reduction length

__global__ __launch_bounds__(256) void conv3x3_kernel(
    const float* __restrict__ x, const float* __restrict__ w,
    const float* __restrict__ bias, float* __restrict__ out)
{
    __shared__ float ws[RTOT][OC];          // transposed weights: [r][oc], 18 KB
    __shared__ float xs[IC][XROWS][XCOLS];  // input band, 13 KB

    const int t    = threadIdx.x;
    const int blk  = blockIdx.x;
    const int band = blk & (NBANDS - 1);
    const int b    = blk >> 3;
    const int row0 = band * ROWS;

    // ---- stage weights transposed: ws[r][oc] = w[oc*144 + r] ----
    // lanes write consecutive LDS words (conflict-free); global reads are
    // strided but w is 18 KB and L2-hot across all 256 blocks.
    for (int idx = t; idx < RTOT * OC; idx += 256) {
        const int oc = idx & (OC - 1);
        const int r  = idx >> 5;
        ((float*)ws)[idx] = w[oc * RTOT + r];
    }

    // ---- stage input band (zero-fill out-of-range rows/cols) ----
    const float* xb = x + b * (IC * SI * SI);
    for (int idx = t; idx < IC * XROWS * XCOLS; idx += 256) {
        const int ic  = idx / (XROWS * XCOLS);
        const int rem = idx - ic * (XROWS * XCOLS);
        const int ii  = rem / XCOLS;
        const int jj  = rem - ii * XCOLS;
        const int gi  = row0 + ii;
        float v = 0.0f;
        if (gi < SI && jj < SI) v = xb[ic * SI * SI + gi * SI + jj];
        ((float*)xs)[idx] = v;
    }
    __syncthreads();

    // ---- per-thread 4-oc x 4-col register tile ----
    const int tp  = t & 31;        // position group within band tile
    const int toc = t >> 5;        // 0..7
    const int oc0 = toc * 4;
    const int il  = tp >> 3;       // local output row 0..3
    const int c   = (tp & 7) * 4;  // col base 0,4,...,28

    float acc[4][4] = {{0.f}};     // [oo][jj]

    #pragma unroll
    for (int ic = 0; ic < IC; ++ic) {
        #pragma unroll
        for (int k1 = 0; k1 < KS; ++k1) {
            // 6-wide sliding x window covering cols c..c+5
            float xw[6];
            #pragma unroll
            for (int q = 0; q < 6; ++q) xw[q] = xs[ic][il + k1][c + q];
            #pragma unroll
            for (int k2 = 0; k2 < KS; ++k2) {
                const float4 w4 =
                    *reinterpret_cast<const float4*>(&ws[ic * 9 + k1 * 3 + k2][oc0]);
                const float wv[4] = {w4.x, w4.y, w4.z, w4.w};
                #pragma unroll
                for (int oo = 0; oo < 4; ++oo) {
                    #pragma unroll
                    for (int jj = 0; jj < 4; ++jj) {
                        acc[oo][jj] = fmaf(wv[oo], xw[k2 + jj], acc[oo][jj]);
                    }
                }
            }
        }
    }

    // ---- epilogue: bias + guarded store ----
    const int i = row0 + il;
    if (i < SO) {
        #pragma unroll
        for (int oo = 0; oo < 4; ++oo) {
            const int oc = oc0 + oo;
            const float bs = bias[oc];
            float* orow = out + ((size_t)(b * OC + oc) * SO + i) * SO;
            #pragma unroll
            for (int jj = 0; jj < 4; ++jj) {
                const int j = c + jj;
                if (j < SO) orow[j] = acc[oo][jj] + bs;
            }
        }
    }
}

extern "C" void kernel_launch(void* const* d_in, const int* in_sizes, int n_in,
                              void* d_out, int out_size, void* d_ws, size_t ws_size,
                              hipStream_t stream) {
    const float* x    = (const float*)d_in[0];
    const float* w    = (const float*)d_in[1];
    const float* bias = (const float*)d_in[2];
    // d_in[3..5] (rows/cols/param_idx) encode a dense 3x3 valid conv — unused.
    float* out = (float*)d_out;

    conv3x3_kernel<<<dim3(BATCH * NBANDS), dim3(256), 0, stream>>>(x, w, bias, out);
}

// Round 2
// 103.160 us; speedup vs baseline: 4.7024x; 4.7024x over previous
//
#include <hip/hip_runtime.h>

#define BATCH 32
#define IC 16
#define OC 32
#define SI 32
#define KS 3
#define SO 30

#define ROWS 4                 // output rows per block band
#define XROWS (ROWS + KS - 1)  // 6 input rows staged
#define XCOLS 34               // 32 input cols + 2 window slack (zero-padded)
#define NBANDS 8               // ceil(30/4)
#define RTOT (IC * KS * KS)    // 144 reduction length

__global__ __launch_bounds__(256) void conv3x3_kernel(
    const float* __restrict__ x, const float* __restrict__ w,
    const float* __restrict__ bias, float* __restrict__ out)
{
    __shared__ float ws[RTOT][OC];          // transposed weights: [r][oc], 18 KB
    __shared__ float xs[IC][XROWS][XCOLS];  // input band, 13 KB

    const int t    = threadIdx.x;
    const int blk  = blockIdx.x;
    const int band = blk & (NBANDS - 1);
    const int b    = blk >> 3;
    const int row0 = band * ROWS;

    // ---- stage weights transposed: ws[r][oc] = w[oc*144 + r] ----
    // LDS writes are lane-consecutive (conflict-free); global reads are
    // strided but w is 18 KB total and L2-hot across all 256 blocks.
    for (int idx = t; idx < RTOT * OC; idx += 256) {
        const int oc = idx & (OC - 1);
        const int r  = idx >> 5;
        ((float*)ws)[idx] = w[oc * RTOT + r];
    }

    // ---- stage input band (zero-fill out-of-range rows/cols) ----
    const float* xb = x + b * (IC * SI * SI);
    for (int idx = t; idx < IC * XROWS * XCOLS; idx += 256) {
        const int ic  = idx / (XROWS * XCOLS);
        const int rem = idx - ic * (XROWS * XCOLS);
        const int ii  = rem / XCOLS;
        const int jj  = rem - ii * XCOLS;
        const int gi  = row0 + ii;
        float v = 0.0f;
        if (gi < SI && jj < SI) v = xb[ic * SI * SI + gi * SI + jj];
        ((float*)xs)[idx] = v;
    }
    __syncthreads();

    // ---- per-thread 4-oc x 4-col register tile ----
    const int tp  = t & 31;        // position group within band tile
    const int toc = t >> 5;        // 0..7
    const int oc0 = toc * 4;
    const int il  = tp >> 3;       // local output row 0..3
    const int c   = (tp & 7) * 4;  // col base 0,4,...,28

    float acc[4][4] = {{0.f}};     // [oo][jj]

    // unroll capped at 2: full unroll (48 iters) exhausted the RF in R1
    // (VGPR=256, ~790 MB spill traffic, 485 us). Body per ic is already
    // 144 FMA : ~24 LDS-read instrs.
    #pragma unroll 2
    for (int ic = 0; ic < IC; ++ic) {
        #pragma unroll
        for (int k1 = 0; k1 < KS; ++k1) {
            // 6-wide sliding x window covering cols c..c+5
            float xw[6];
            #pragma unroll
            for (int q = 0; q < 6; ++q) xw[q] = xs[ic][il + k1][c + q];
            #pragma unroll
            for (int k2 = 0; k2 < KS; ++k2) {
                const float4 w4 =
                    *reinterpret_cast<const float4*>(&ws[ic * 9 + k1 * 3 + k2][oc0]);
                const float wv[4] = {w4.x, w4.y, w4.z, w4.w};
                #pragma unroll
                for (int oo = 0; oo < 4; ++oo) {
                    #pragma unroll
                    for (int jj = 0; jj < 4; ++jj) {
                        acc[oo][jj] = fmaf(wv[oo], xw[k2 + jj], acc[oo][jj]);
                    }
                }
            }
        }
    }

    // ---- epilogue: bias + guarded store (float4 fast path for c<28) ----
    const int i = row0 + il;
    if (i < SO) {
        #pragma unroll
        for (int oo = 0; oo < 4; ++oo) {
            const int oc = oc0 + oo;
            const float bs = bias[oc];
            float* orow = out + ((size_t)(b * OC + oc) * SO + i) * SO;
            if (c + 3 < SO) {
                float4 v = make_float4(acc[oo][0] + bs, acc[oo][1] + bs,
                                       acc[oo][2] + bs, acc[oo][3] + bs);
                *reinterpret_cast<float4*>(&orow[c]) = v;
            } else {
                #pragma unroll
                for (int jj = 0; jj < 4; ++jj) {
                    const int j = c + jj;
                    if (j < SO) orow[j] = acc[oo][jj] + bs;
                }
            }
        }
    }
}

extern "C" void kernel_launch(void* const* d_in, const int* in_sizes, int n_in,
                              void* d_out, int out_size, void* d_ws, size_t ws_size,
                              hipStream_t stream) {
    const float* x    = (const float*)d_in[0];
    const float* w    = (const float*)d_in[1];
    const float* bias = (const float*)d_in[2];
    // d_in[3..5] (rows/cols/param_idx) encode a dense 3x3 valid conv — unused.
    float* out = (float*)d_out;

    conv3x3_kernel<<<dim3(BATCH * NBANDS), dim3(256), 0, stream>>>(x, w, bias, out);
}